// Round 1
// baseline (34041.013 us; speedup 1.0000x reference)
//
#include <hip/hip_runtime.h>
#include <hip/hip_cooperative_groups.h>
#include <cstdint>
#include <cstddef>

// ---------------------------------------------------------------------------
// Problem constants (ARU recurrence): B=32, S=1024, H=1024, 3H=3072
// ---------------------------------------------------------------------------
#define HID   1024
#define BATCH 32
#define SEQ   1024
#define NROWS 32768   /* BATCH*SEQ */
#define G3    3072

typedef __attribute__((ext_vector_type(8))) short bf16x8_t;
typedef __attribute__((ext_vector_type(4))) float f32x4_t;

__device__ __forceinline__ unsigned short f2bf(float f) {
  unsigned u = __float_as_uint(f);
  u += 0x7FFFu + ((u >> 16) & 1u);       // round-to-nearest-even
  return (unsigned short)(u >> 16);
}
__device__ __forceinline__ float bf2f(unsigned short s) {
  return __uint_as_float(((unsigned)s) << 16);
}

// ---------------------------------------------------------------------------
// K0: transpose + cast  W (1024 x N) fp32  ->  WT (N x 1024) bf16
// ---------------------------------------------------------------------------
__global__ __launch_bounds__(256) void transpose_cast(const float* __restrict__ in,
                                                      unsigned short* __restrict__ out,
                                                      int N) {
  __shared__ float tile[32][33];
  int k0 = blockIdx.x * 32, n0 = blockIdx.y * 32;
  int tx = threadIdx.x, ty = threadIdx.y;   // (32,8)
#pragma unroll
  for (int i = 0; i < 4; ++i)
    tile[ty + 8 * i][tx] = in[(size_t)(k0 + ty + 8 * i) * N + n0 + tx];
  __syncthreads();
#pragma unroll
  for (int i = 0; i < 4; ++i)
    out[(size_t)(n0 + ty + 8 * i) * HID + k0 + tx] = f2bf(tile[tx][ty + 8 * i]);
}

// ---------------------------------------------------------------------------
// K1: e = bf16(embed[x])   (32768 x 1024)
// ---------------------------------------------------------------------------
__global__ __launch_bounds__(256) void gather_cast(const int* __restrict__ x,
                                                   const float* __restrict__ embed,
                                                   unsigned short* __restrict__ e) {
  int r = blockIdx.x;
  int t = threadIdx.x;
  int tok = x[r];
  const float4* src = (const float4*)(embed + (size_t)tok * HID);
  float4 v = src[t];
  ushort4 o;
  o.x = f2bf(v.x); o.y = f2bf(v.y); o.z = f2bf(v.z); o.w = f2bf(v.w);
  ((ushort4*)(e + (size_t)r * HID))[t] = o;
}

// ---------------------------------------------------------------------------
// K2: fused GEMM  C = e(32768x1024) @ B'(1024x4096)   [B' stored as (4096x1024) n-major]
//     cols [0,3072): gate_x = C + bgx   (bf16 out)
//     cols [3072,4096): cand = tanh(C + bc) (bf16 out)
// 128x128 tile, BK=32, 256 threads (4 waves, 2x2), 4x4 16x16x32 MFMA per wave.
// ---------------------------------------------------------------------------
__global__ __launch_bounds__(256) void gemm_fused(const unsigned short* __restrict__ A,
                                                  const unsigned short* __restrict__ B,
                                                  const float* __restrict__ bgx,
                                                  const float* __restrict__ bc,
                                                  unsigned short* __restrict__ gx,
                                                  unsigned short* __restrict__ cand) {
  __shared__ unsigned short As[128 * 32];
  __shared__ unsigned short Bs[128 * 32];
  const int bm = blockIdx.x * 128, bn = blockIdx.y * 128;
  const int t = threadIdx.x;
  const int wave = t >> 6, lane = t & 63;
  const int q = lane >> 4, nidx = lane & 15;
  const int wm = (wave & 1) * 64, wn = (wave >> 1) * 64;
  const int sr = t >> 2;             // staging row base (0..63)
  const int kofs = (t & 3) * 8;      // staging k offset

  f32x4_t acc[4][4];
#pragma unroll
  for (int i = 0; i < 4; ++i)
#pragma unroll
    for (int j = 0; j < 4; ++j) acc[i][j] = (f32x4_t){0.f, 0.f, 0.f, 0.f};

#pragma unroll 1
  for (int kt = 0; kt < HID; kt += 32) {
    __syncthreads();
#pragma unroll
    for (int c = 0; c < 2; ++c) {
      int row = c * 64 + sr;
      *(uint4*)(&As[row * 32 + kofs]) = *(const uint4*)(&A[(size_t)(bm + row) * HID + kt + kofs]);
      *(uint4*)(&Bs[row * 32 + kofs]) = *(const uint4*)(&B[(size_t)(bn + row) * HID + kt + kofs]);
    }
    __syncthreads();
    bf16x8_t af[4], bfr[4];
#pragma unroll
    for (int i = 0; i < 4; ++i)
      af[i] = *(const bf16x8_t*)(&As[(wm + i * 16 + nidx) * 32 + q * 8]);
#pragma unroll
    for (int j = 0; j < 4; ++j)
      bfr[j] = *(const bf16x8_t*)(&Bs[(wn + j * 16 + nidx) * 32 + q * 8]);
#pragma unroll
    for (int i = 0; i < 4; ++i)
#pragma unroll
      for (int j = 0; j < 4; ++j)
        acc[i][j] = __builtin_amdgcn_mfma_f32_16x16x32_bf16(af[i], bfr[j], acc[i][j], 0, 0, 0);
  }

  // epilogue: C/D layout col=lane&15, row=quad*4+reg
#pragma unroll
  for (int i = 0; i < 4; ++i) {
#pragma unroll
    for (int j = 0; j < 4; ++j) {
#pragma unroll
      for (int reg = 0; reg < 4; ++reg) {
        int m = bm + wm + i * 16 + q * 4 + reg;
        int n = bn + wn + j * 16 + nidx;
        float v = acc[i][j][reg];
        if (n < G3) {
          gx[(size_t)m * G3 + n] = f2bf(v + bgx[n]);
        } else {
          int nc = n - G3;
          cand[(size_t)m * HID + nc] = f2bf(tanhf(v + bc[nc]));
        }
      }
    }
  }
}

// ---------------------------------------------------------------------------
// K3: cooperative recurrence. 256 WGs x 128 thr (2 waves; wave = batch half).
// WG g owns j in {4g..4g+3}; LDS holds Wgh^T rows {j, 1024+j, 2048+j} (16x1024 bf16,
// rows 12..15 zero). Per step: MFMA (16x16x32) h@Wgh_slice, sigmoid, shuffle-combine,
// fp32 h carried in registers, bf16 h broadcast via ping-pong global buffer.
// ---------------------------------------------------------------------------
__global__ __launch_bounds__(128) void recurrence(const unsigned short* __restrict__ gx,
                                                  const unsigned short* __restrict__ cand,
                                                  const unsigned short* __restrict__ WghT,
                                                  unsigned short* __restrict__ h0,
                                                  unsigned short* __restrict__ h1,
                                                  float* __restrict__ out) {
  const int g = blockIdx.x;          // 0..255 -> j block [4g,4g+4)
  const int tid = threadIdx.x;
  const int wave = tid >> 6;         // 0: batches 0-15, 1: batches 16-31
  const int lane = tid & 63;
  const int q = lane >> 4, n = lane & 15;
  const int b_base = wave * 16;

  __shared__ unsigned short Bs[16 * 1024];   // [n][k] bf16, 32 KB

  // stage Wgh^T slice: row n' < 12 -> global row (n'>>2)*1024 + 4g + (n'&3)
  for (int row = 0; row < 16; ++row) {
    uint4* d = (uint4*)(&Bs[row * 1024]);
    if (row < 12) {
      int grow = (row >> 2) * HID + g * 4 + (row & 3);
      const uint4* s = (const uint4*)(&WghT[(size_t)grow * HID]);
      d[tid] = s[tid];
    } else {
      d[tid] = (uint4){0u, 0u, 0u, 0u};
    }
  }
  __syncthreads();

  const int cg = (n >> 2) * HID + g * 4 + (n & 3);   // gx col for lane (valid n<12)
  float h_own[4] = {0.f, 0.f, 0.f, 0.f};             // fp32 h for (b_base+q*4+r, j=4g+n), n<4

  cooperative_groups::grid_group grid = cooperative_groups::this_grid();

#pragma unroll 1
  for (int t = 0; t < SEQ; ++t) {
    const unsigned short* hc = (t & 1) ? h1 : h0;
    unsigned short* hn = (t & 1) ? h0 : h1;

    // prefetch gate_x and cand for this step (issue before MFMA loop)
    float gxv[4] = {0.f, 0.f, 0.f, 0.f};
    if (n < 12) {
#pragma unroll
      for (int r = 0; r < 4; ++r) {
        int b = b_base + q * 4 + r;
        gxv[r] = bf2f(gx[((size_t)b * SEQ + t) * G3 + cg]);
      }
    }
    float vv[4] = {0.f, 0.f, 0.f, 0.f};
    if (n < 4) {
#pragma unroll
      for (int r = 0; r < 4; ++r) {
        int b = b_base + q * 4 + r;
        vv[r] = bf2f(cand[((size_t)b * SEQ + t) * HID + g * 4 + n]);
      }
    }

    // preact = h @ Wgh_slice : A-frag from global bf16 h, B-frag from LDS
    f32x4_t acc = (f32x4_t){0.f, 0.f, 0.f, 0.f};
#pragma unroll 8
    for (int kt = 0; kt < 32; ++kt) {
      bf16x8_t bfr = *(const bf16x8_t*)(&Bs[n * 1024 + kt * 32 + q * 8]);
      bf16x8_t a = *(const bf16x8_t*)(&hc[(size_t)(b_base + n) * HID + kt * 32 + q * 8]);
      acc = __builtin_amdgcn_mfma_f32_16x16x32_bf16(a, bfr, acc, 0, 0, 0);
    }

    // gates + combine. D layout: col(n)=lane&15, row(batch)=q*4+reg.
#pragma unroll
    for (int r = 0; r < 4; ++r) {
      float pre = acc[r] + gxv[r];
      float gval = 1.f / (1.f + __expf(-pre));
      float piv = __shfl(gval, (lane & 48) + (n & 3) + 4, 64);
      float alv = __shfl(gval, (lane & 48) + (n & 3) + 8, 64);
      if (n < 4) {
        float hv = gval * (piv * h_own[r] + alv * vv[r]);
        h_own[r] = hv;
        int b = b_base + q * 4 + r;
        hn[(size_t)b * HID + g * 4 + n] = f2bf(hv);
      }
    }

    grid.sync();
  }

  if (n < 4) {
#pragma unroll
    for (int r = 0; r < 4; ++r) {
      int b = b_base + q * 4 + r;
      out[(size_t)b * HID + g * 4 + n] = h_own[r];
    }
  }
}

// ---------------------------------------------------------------------------
// launcher
// ---------------------------------------------------------------------------
extern "C" void kernel_launch(void* const* d_in, const int* in_sizes, int n_in,
                              void* d_out, int out_size, void* d_ws, size_t ws_size,
                              hipStream_t stream) {
  const int*   x     = (const int*)d_in[0];
  const float* embed = (const float*)d_in[1];
  const float* Wc    = (const float*)d_in[2];
  const float* bc    = (const float*)d_in[3];
  const float* Wgx   = (const float*)d_in[4];
  const float* bgx   = (const float*)d_in[5];
  const float* Wgh   = (const float*)d_in[6];
  float* out = (float*)d_out;

  char* base = (char*)d_ws;
  unsigned short* e    = (unsigned short*)(base);                       // 32768x1024 bf16 = 64 MiB
  unsigned short* Bp   = (unsigned short*)(base + 67108864);            // 4096x1024 bf16  = 8 MiB
  unsigned short* WghT = (unsigned short*)(base + 75497472);            // 3072x1024 bf16  = 6 MiB
  unsigned short* gxb  = (unsigned short*)(base + 81788928);            // 32768x3072 bf16 = 192 MiB
  unsigned short* cnd  = (unsigned short*)(base + 283115520);           // 32768x1024 bf16 = 64 MiB
  unsigned short* h0   = (unsigned short*)(base + 350224384);           // 32x1024 bf16
  unsigned short* h1   = (unsigned short*)(base + 350289920);           // 32x1024 bf16

  // K0: weight transposes (fp32 -> bf16, n-major)
  transpose_cast<<<dim3(32, 96), dim3(32, 8), 0, stream>>>(Wgx, Bp, G3);
  transpose_cast<<<dim3(32, 32), dim3(32, 8), 0, stream>>>(Wc, Bp + (size_t)G3 * HID, HID);
  transpose_cast<<<dim3(32, 96), dim3(32, 8), 0, stream>>>(Wgh, WghT, G3);

  // K1: embedding gather + cast
  gather_cast<<<dim3(NROWS), dim3(256), 0, stream>>>(x, embed, e);

  // K2: fused GEMM -> gate_x (+bgx) and cand (tanh)
  gemm_fused<<<dim3(256, 32), dim3(256), 0, stream>>>(e, Bp, bgx, bc, gxb, cnd);

  // zero h0 (ws is poisoned 0xAA before each call)
  hipMemsetAsync(h0, 0, 65536, stream);

  // K3: cooperative recurrence
  void* args[] = {(void*)&gxb, (void*)&cnd, (void*)&WghT, (void*)&h0, (void*)&h1, (void*)&out};
  hipLaunchCooperativeKernel((const void*)recurrence, dim3(256), dim3(128), args, 0, stream);
}

// Round 2
// 13494.231 us; speedup vs baseline: 2.5226x; 2.5226x over previous
//
#include <hip/hip_runtime.h>
#include <cstdint>
#include <cstddef>

// ---------------------------------------------------------------------------
// Problem constants (ARU recurrence): B=32, S=1024, H=1024, 3H=3072
// ---------------------------------------------------------------------------
#define HID   1024
#define BATCH 32
#define SEQ   1024
#define NROWS 32768   /* BATCH*SEQ */
#define G3    3072
#define NWG   128     /* recurrence workgroups; each owns 8 h-columns */

typedef __attribute__((ext_vector_type(8))) short bf16x8_t;
typedef __attribute__((ext_vector_type(4))) float f32x4_t;

__device__ __forceinline__ unsigned short f2bf(float f) {
  unsigned u = __float_as_uint(f);
  u += 0x7FFFu + ((u >> 16) & 1u);       // round-to-nearest-even
  return (unsigned short)(u >> 16);
}
__device__ __forceinline__ float bf2f(unsigned short s) {
  return __uint_as_float(((unsigned)s) << 16);
}

// ---------------------------------------------------------------------------
// K0: transpose + cast  W (1024 x N) fp32  ->  WT (N x 1024) bf16
// ---------------------------------------------------------------------------
__global__ __launch_bounds__(256) void transpose_cast(const float* __restrict__ in,
                                                      unsigned short* __restrict__ out,
                                                      int N) {
  __shared__ float tile[32][33];
  int k0 = blockIdx.x * 32, n0 = blockIdx.y * 32;
  int tx = threadIdx.x, ty = threadIdx.y;   // (32,8)
#pragma unroll
  for (int i = 0; i < 4; ++i)
    tile[ty + 8 * i][tx] = in[(size_t)(k0 + ty + 8 * i) * N + n0 + tx];
  __syncthreads();
#pragma unroll
  for (int i = 0; i < 4; ++i)
    out[(size_t)(n0 + ty + 8 * i) * HID + k0 + tx] = f2bf(tile[tx][ty + 8 * i]);
}

// ---------------------------------------------------------------------------
// K1: e = bf16(embed[x])   (32768 x 1024)
// ---------------------------------------------------------------------------
__global__ __launch_bounds__(256) void gather_cast(const int* __restrict__ x,
                                                   const float* __restrict__ embed,
                                                   unsigned short* __restrict__ e) {
  int r = blockIdx.x;
  int t = threadIdx.x;
  int tok = x[r];
  const float4* src = (const float4*)(embed + (size_t)tok * HID);
  float4 v = src[t];
  ushort4 o;
  o.x = f2bf(v.x); o.y = f2bf(v.y); o.z = f2bf(v.z); o.w = f2bf(v.w);
  ((ushort4*)(e + (size_t)r * HID))[t] = o;
}

// ---------------------------------------------------------------------------
// K2: fused GEMM  C = e(32768x1024) @ B'(1024x4096)   [B' stored as (4096x1024) n-major]
//     cols [0,3072): gate_x = C + bgx   (bf16 out)
//     cols [3072,4096): cand = tanh(C + bc) (bf16 out)
// ---------------------------------------------------------------------------
__global__ __launch_bounds__(256) void gemm_fused(const unsigned short* __restrict__ A,
                                                  const unsigned short* __restrict__ B,
                                                  const float* __restrict__ bgx,
                                                  const float* __restrict__ bc,
                                                  unsigned short* __restrict__ gx,
                                                  unsigned short* __restrict__ cand) {
  __shared__ unsigned short As[128 * 32];
  __shared__ unsigned short Bs[128 * 32];
  const int bm = blockIdx.x * 128, bn = blockIdx.y * 128;
  const int t = threadIdx.x;
  const int wave = t >> 6, lane = t & 63;
  const int q = lane >> 4, nidx = lane & 15;
  const int wm = (wave & 1) * 64, wn = (wave >> 1) * 64;
  const int sr = t >> 2;
  const int kofs = (t & 3) * 8;

  f32x4_t acc[4][4];
#pragma unroll
  for (int i = 0; i < 4; ++i)
#pragma unroll
    for (int j = 0; j < 4; ++j) acc[i][j] = (f32x4_t){0.f, 0.f, 0.f, 0.f};

#pragma unroll 1
  for (int kt = 0; kt < HID; kt += 32) {
    __syncthreads();
#pragma unroll
    for (int c = 0; c < 2; ++c) {
      int row = c * 64 + sr;
      *(uint4*)(&As[row * 32 + kofs]) = *(const uint4*)(&A[(size_t)(bm + row) * HID + kt + kofs]);
      *(uint4*)(&Bs[row * 32 + kofs]) = *(const uint4*)(&B[(size_t)(bn + row) * HID + kt + kofs]);
    }
    __syncthreads();
    bf16x8_t af[4], bfr[4];
#pragma unroll
    for (int i = 0; i < 4; ++i)
      af[i] = *(const bf16x8_t*)(&As[(wm + i * 16 + nidx) * 32 + q * 8]);
#pragma unroll
    for (int j = 0; j < 4; ++j)
      bfr[j] = *(const bf16x8_t*)(&Bs[(wn + j * 16 + nidx) * 32 + q * 8]);
#pragma unroll
    for (int i = 0; i < 4; ++i)
#pragma unroll
      for (int j = 0; j < 4; ++j)
        acc[i][j] = __builtin_amdgcn_mfma_f32_16x16x32_bf16(af[i], bfr[j], acc[i][j], 0, 0, 0);
  }

#pragma unroll
  for (int i = 0; i < 4; ++i) {
#pragma unroll
    for (int j = 0; j < 4; ++j) {
#pragma unroll
      for (int reg = 0; reg < 4; ++reg) {
        int m = bm + wm + i * 16 + q * 4 + reg;
        int n = bn + wn + j * 16 + nidx;
        float v = acc[i][j][reg];
        if (n < G3) {
          gx[(size_t)m * G3 + n] = f2bf(v + bgx[n]);
        } else {
          int nc = n - G3;
          cand[(size_t)m * HID + nc] = f2bf(tanhf(v + bc[nc]));
        }
      }
    }
  }
}

// ---------------------------------------------------------------------------
// K3a: init per-step barrier counters + zero h0.
// ready[0]=NWG (h(0)=0 is pre-published), ready[1..1024]=0.
// ---------------------------------------------------------------------------
__global__ __launch_bounds__(256) void init_state(unsigned int* __restrict__ ready,
                                                  unsigned short* __restrict__ h0) {
  int t = blockIdx.x * 256 + threadIdx.x;
  if (t <= SEQ) ready[t] = (t == 0) ? (unsigned)NWG : 0u;
  for (int i = t; i < BATCH * HID; i += 5 * 256) h0[i] = 0;
}

// ---------------------------------------------------------------------------
// K3: recurrence, hand-rolled per-step barrier (no grid.sync).
// NWG=128 WGs x 128 thr (2 waves; wave = batch half). WG g owns h-cols
// [8g, 8g+8). LDS: 2 swizzled 16x1024 bf16 B-tiles (64 KB):
//   tile0 cols = [rho j=8g..8g+7 | pi j=8g..8g+7], tile1 = [alpha .. | zeros].
// One lane holds rho+alpha for its (b,j); pi fetched with one __shfl.
// h carried fp32 in regs; bf16 h ping-pong via global; per-step visibility via
// agent-scope release/acquire fences + one atomicAdd per WG.
// ---------------------------------------------------------------------------
__global__ __launch_bounds__(128) void recurrence(const unsigned short* __restrict__ gx,
                                                  const unsigned short* __restrict__ cand,
                                                  const unsigned short* __restrict__ WghT,
                                                  unsigned short* __restrict__ h0,
                                                  unsigned short* __restrict__ h1,
                                                  unsigned int* __restrict__ ready,
                                                  float* __restrict__ out) {
  const int g = blockIdx.x;          // owns h-cols [8g, 8g+8)
  const int tid = threadIdx.x;
  const int w = tid >> 6;            // batch half
  const int lane = tid & 63;
  const int q = lane >> 4, n = lane & 15;

  __shared__ __align__(16) unsigned short Bs[32 * 1024];   // 64 KB exactly

  // stage Wgh^T slices, XOR-swizzled in 16B units: row r, chunk c16 ->
  // byte (r*128 + (c16 ^ (r&7))) * 16. Makes ds_read_b128 conflict-free.
  for (int it = tid; it < 4096; it += 128) {
    int row = it >> 7, c16 = it & 127;
    int tile = row >> 4, rr = row & 15;
    uint4 val = {0u, 0u, 0u, 0u};
    if (tile == 0) {
      int gr = (rr < 8) ? (8 * g + rr) : (1024 + 8 * g + (rr - 8));
      val = ((const uint4*)(WghT + (size_t)gr * HID))[c16];
    } else if (rr < 8) {
      int gr = 2048 + 8 * g + rr;
      val = ((const uint4*)(WghT + (size_t)gr * HID))[c16];
    }
    *(uint4*)((char*)Bs + (size_t)(row * 128 + (c16 ^ (row & 7))) * 16) = val;
  }
  __syncthreads();

  float h_own[4] = {0.f, 0.f, 0.f, 0.f};
  const int c_rp = (n < 8) ? (8 * g + n) : (1024 + 8 * g + (n - 8)); // rho|pi col
  const int c_al = 2048 + 8 * g + (n & 7);                            // alpha col
  const int c_h  = 8 * g + (n & 7);                                   // h/cand col

  const char* b0p = (const char*)Bs + (size_t)n * 2048;
  const char* b1p = b0p + 16 * 2048;

#pragma unroll 1
  for (int t = 0; t < SEQ; ++t) {
    const unsigned short* hc = (t & 1) ? h1 : h0;
    unsigned short* hn = (t & 1) ? h0 : h1;

    // issue gx/cand loads BEFORE the spin: latency hides behind barrier wait
    float g0v[4], g1v[4], vv[4];
#pragma unroll
    for (int r = 0; r < 4; ++r) {
      size_t rb = ((size_t)(w * 16 + q * 4 + r) * SEQ + t);
      g0v[r] = bf2f(gx[rb * G3 + c_rp]);
      g1v[r] = bf2f(gx[rb * G3 + c_al]);
      vv[r]  = bf2f(cand[rb * HID + c_h]);
    }

    // wait until all WGs published h(t)
    if (tid == 0) {
      while (__hip_atomic_load(&ready[t], __ATOMIC_RELAXED, __HIP_MEMORY_SCOPE_AGENT) < (unsigned)NWG)
        __builtin_amdgcn_s_sleep(1);
    }
    __syncthreads();
    __builtin_amdgcn_fence(__ATOMIC_ACQUIRE, "agent");   // invalidate L1/L2 before h loads

    // preact = h(t) @ Wgh_slice
    f32x4_t acc0 = (f32x4_t){0.f, 0.f, 0.f, 0.f};
    f32x4_t acc1 = (f32x4_t){0.f, 0.f, 0.f, 0.f};
    const unsigned short* ha = hc + (size_t)(w * 16 + n) * HID + q * 8;
#pragma unroll 8
    for (int kt = 0; kt < 32; ++kt) {
      bf16x8_t a = *(const bf16x8_t*)(ha + kt * 32);
      int sw = ((kt * 4 + q) ^ (n & 7)) * 16;
      bf16x8_t b0 = *(const bf16x8_t*)(b0p + sw);
      bf16x8_t b1 = *(const bf16x8_t*)(b1p + sw);
      acc0 = __builtin_amdgcn_mfma_f32_16x16x32_bf16(a, b0, acc0, 0, 0, 0);
      acc1 = __builtin_amdgcn_mfma_f32_16x16x32_bf16(a, b1, acc1, 0, 0, 0);
    }

    // gates + carry. D layout: col=lane&15, row(batch)=q*4+r.
#pragma unroll
    for (int r = 0; r < 4; ++r) {
      float s0 = 1.f / (1.f + __expf(-(acc0[r] + g0v[r])));   // rho (n<8) / pi (n>=8)
      float al = 1.f / (1.f + __expf(-(acc1[r] + g1v[r])));   // alpha (n<8)
      float piv = __shfl(s0, q * 16 + 8 + (n & 7), 64);
      if (n < 8) {
        h_own[r] = s0 * (piv * h_own[r] + al * vv[r]);
        hn[(size_t)(w * 16 + q * 4 + r) * HID + c_h] = f2bf(h_own[r]);
      }
    }

    // publish h(t+1): drain stores + writeback L2, then one arrive per WG
    __builtin_amdgcn_fence(__ATOMIC_RELEASE, "agent");
    __syncthreads();
    if (tid == 0)
      __hip_atomic_fetch_add(&ready[t + 1], 1u, __ATOMIC_RELAXED, __HIP_MEMORY_SCOPE_AGENT);
  }

#pragma unroll
  for (int r = 0; r < 4; ++r)
    if (n < 8)
      out[(size_t)(w * 16 + q * 4 + r) * HID + c_h] = h_own[r];
}

// ---------------------------------------------------------------------------
// launcher
// ---------------------------------------------------------------------------
extern "C" void kernel_launch(void* const* d_in, const int* in_sizes, int n_in,
                              void* d_out, int out_size, void* d_ws, size_t ws_size,
                              hipStream_t stream) {
  const int*   x     = (const int*)d_in[0];
  const float* embed = (const float*)d_in[1];
  const float* Wc    = (const float*)d_in[2];
  const float* bc    = (const float*)d_in[3];
  const float* Wgx   = (const float*)d_in[4];
  const float* bgx   = (const float*)d_in[5];
  const float* Wgh   = (const float*)d_in[6];
  float* out = (float*)d_out;

  char* base = (char*)d_ws;
  unsigned short* e    = (unsigned short*)(base);                       // 32768x1024 bf16 = 64 MiB
  unsigned short* Bp   = (unsigned short*)(base + 67108864);            // 4096x1024 bf16  = 8 MiB
  unsigned short* WghT = (unsigned short*)(base + 75497472);            // 3072x1024 bf16  = 6 MiB
  unsigned short* gxb  = (unsigned short*)(base + 81788928);            // 32768x3072 bf16 = 192 MiB
  unsigned short* cnd  = (unsigned short*)(base + 283115520);           // 32768x1024 bf16 = 64 MiB
  unsigned short* h0   = (unsigned short*)(base + 350224384);           // 32x1024 bf16
  unsigned short* h1   = (unsigned short*)(base + 350289920);           // 32x1024 bf16
  // barrier counters live at base (e region) — e is dead after gemm_fused,
  // and init_state runs after gemm_fused in stream order.
  unsigned int*   ready = (unsigned int*)(base);                        // 1025 u32

  transpose_cast<<<dim3(32, 96), dim3(32, 8), 0, stream>>>(Wgx, Bp, G3);
  transpose_cast<<<dim3(32, 32), dim3(32, 8), 0, stream>>>(Wc, Bp + (size_t)G3 * HID, HID);
  transpose_cast<<<dim3(32, 96), dim3(32, 8), 0, stream>>>(Wgh, WghT, G3);

  gather_cast<<<dim3(NROWS), dim3(256), 0, stream>>>(x, embed, e);

  gemm_fused<<<dim3(256, 32), dim3(256), 0, stream>>>(e, Bp, bgx, bc, gxb, cnd);

  // init barrier counters + h0 AFTER gemm (ready aliases e's storage)
  init_state<<<dim3(5), dim3(256), 0, stream>>>(ready, h0);

  // co-residency guaranteed: 128 WGs, 64 KB LDS each -> >=1 per CU on 256 CUs
  void* args[] = {(void*)&gxb, (void*)&cnd, (void*)&WghT, (void*)&h0, (void*)&h1,
                  (void*)&ready, (void*)&out};
  hipLaunchCooperativeKernel((const void*)recurrence, dim3(NWG), dim3(128), args, 0, stream);
}

// Round 3
// 12355.392 us; speedup vs baseline: 2.7552x; 1.0922x over previous
//
#include <hip/hip_runtime.h>
#include <cstdint>
#include <cstddef>

// ---------------------------------------------------------------------------
// Problem constants (ARU recurrence): B=32, S=1024, H=1024, 3H=3072
// ---------------------------------------------------------------------------
#define HID   1024
#define BATCH 32
#define SEQ   1024
#define NROWS 32768   /* BATCH*SEQ */
#define G3    3072
#define NWG   128     /* recurrence workgroups; each owns 8 h-columns */
#define NFLAGS ((SEQ + 1) * NWG)

typedef __attribute__((ext_vector_type(8))) short bf16x8_t;
typedef __attribute__((ext_vector_type(4))) float f32x4_t;

__device__ __forceinline__ unsigned short f2bf(float f) {
  unsigned u = __float_as_uint(f);
  u += 0x7FFFu + ((u >> 16) & 1u);       // round-to-nearest-even
  return (unsigned short)(u >> 16);
}
__device__ __forceinline__ float bf2f(unsigned short s) {
  return __uint_as_float(((unsigned)s) << 16);
}

// ---------------------------------------------------------------------------
// K0: transpose + cast  W (1024 x N) fp32  ->  WT (N x 1024) bf16
// ---------------------------------------------------------------------------
__global__ __launch_bounds__(256) void transpose_cast(const float* __restrict__ in,
                                                      unsigned short* __restrict__ out,
                                                      int N) {
  __shared__ float tile[32][33];
  int k0 = blockIdx.x * 32, n0 = blockIdx.y * 32;
  int tx = threadIdx.x, ty = threadIdx.y;   // (32,8)
#pragma unroll
  for (int i = 0; i < 4; ++i)
    tile[ty + 8 * i][tx] = in[(size_t)(k0 + ty + 8 * i) * N + n0 + tx];
  __syncthreads();
#pragma unroll
  for (int i = 0; i < 4; ++i)
    out[(size_t)(n0 + ty + 8 * i) * HID + k0 + tx] = f2bf(tile[tx][ty + 8 * i]);
}

// ---------------------------------------------------------------------------
// K1: e = bf16(embed[x])   (32768 x 1024)
// ---------------------------------------------------------------------------
__global__ __launch_bounds__(256) void gather_cast(const int* __restrict__ x,
                                                   const float* __restrict__ embed,
                                                   unsigned short* __restrict__ e) {
  int r = blockIdx.x;
  int t = threadIdx.x;
  int tok = x[r];
  const float4* src = (const float4*)(embed + (size_t)tok * HID);
  float4 v = src[t];
  ushort4 o;
  o.x = f2bf(v.x); o.y = f2bf(v.y); o.z = f2bf(v.z); o.w = f2bf(v.w);
  ((ushort4*)(e + (size_t)r * HID))[t] = o;
}

// ---------------------------------------------------------------------------
// K2: fused GEMM  C = e(32768x1024) @ B'(1024x4096)   [B' stored as (4096x1024) n-major]
//     cols [0,3072): gate_x = C + bgx   (bf16 out)
//     cols [3072,4096): cand = tanh(C + bc) (bf16 out)
// ---------------------------------------------------------------------------
__global__ __launch_bounds__(256) void gemm_fused(const unsigned short* __restrict__ A,
                                                  const unsigned short* __restrict__ B,
                                                  const float* __restrict__ bgx,
                                                  const float* __restrict__ bc,
                                                  unsigned short* __restrict__ gx,
                                                  unsigned short* __restrict__ cand) {
  __shared__ unsigned short As[128 * 32];
  __shared__ unsigned short Bs[128 * 32];
  const int bm = blockIdx.x * 128, bn = blockIdx.y * 128;
  const int t = threadIdx.x;
  const int wave = t >> 6, lane = t & 63;
  const int q = lane >> 4, nidx = lane & 15;
  const int wm = (wave & 1) * 64, wn = (wave >> 1) * 64;
  const int sr = t >> 2;
  const int kofs = (t & 3) * 8;

  f32x4_t acc[4][4];
#pragma unroll
  for (int i = 0; i < 4; ++i)
#pragma unroll
    for (int j = 0; j < 4; ++j) acc[i][j] = (f32x4_t){0.f, 0.f, 0.f, 0.f};

#pragma unroll 1
  for (int kt = 0; kt < HID; kt += 32) {
    __syncthreads();
#pragma unroll
    for (int c = 0; c < 2; ++c) {
      int row = c * 64 + sr;
      *(uint4*)(&As[row * 32 + kofs]) = *(const uint4*)(&A[(size_t)(bm + row) * HID + kt + kofs]);
      *(uint4*)(&Bs[row * 32 + kofs]) = *(const uint4*)(&B[(size_t)(bn + row) * HID + kt + kofs]);
    }
    __syncthreads();
    bf16x8_t af[4], bfr[4];
#pragma unroll
    for (int i = 0; i < 4; ++i)
      af[i] = *(const bf16x8_t*)(&As[(wm + i * 16 + nidx) * 32 + q * 8]);
#pragma unroll
    for (int j = 0; j < 4; ++j)
      bfr[j] = *(const bf16x8_t*)(&Bs[(wn + j * 16 + nidx) * 32 + q * 8]);
#pragma unroll
    for (int i = 0; i < 4; ++i)
#pragma unroll
      for (int j = 0; j < 4; ++j)
        acc[i][j] = __builtin_amdgcn_mfma_f32_16x16x32_bf16(af[i], bfr[j], acc[i][j], 0, 0, 0);
  }

#pragma unroll
  for (int i = 0; i < 4; ++i) {
#pragma unroll
    for (int j = 0; j < 4; ++j) {
#pragma unroll
      for (int reg = 0; reg < 4; ++reg) {
        int m = bm + wm + i * 16 + q * 4 + reg;
        int n = bn + wn + j * 16 + nidx;
        float v = acc[i][j][reg];
        if (n < G3) {
          gx[(size_t)m * G3 + n] = f2bf(v + bgx[n]);
        } else {
          int nc = n - G3;
          cand[(size_t)m * HID + nc] = f2bf(tanhf(v + bc[nc]));
        }
      }
    }
  }
}

// ---------------------------------------------------------------------------
// K3a: init distributed barrier flags + zero h0.
// flags[0][g]=1 for all g (h(0)=0 pre-published); flags[1..SEQ][*]=0.
// ---------------------------------------------------------------------------
__global__ __launch_bounds__(256) void init_state(unsigned int* __restrict__ flags,
                                                  unsigned short* __restrict__ h0) {
  int t = blockIdx.x * 256 + threadIdx.x;   // grid 513*256 covers NFLAGS=131200
  if (t < NFLAGS) flags[t] = (t < NWG) ? 1u : 0u;
  for (int i = t; i < BATCH * HID; i += 513 * 256) h0[i] = 0;
}

// ---------------------------------------------------------------------------
// K3: recurrence with DISTRIBUTED flag barrier (no central atomic).
// NWG=128 WGs x 128 thr (2 waves; wave = batch half). WG g owns h-cols
// [8g, 8g+8). LDS: 2 swizzled 16x1024 bf16 B-tiles (64 KB).
// Producer: plain h stores -> release-agent fence (per wave) -> syncthreads ->
// tid0 sets flags[t+1][g] (relaxed agent write-through). Consumer: lane tid
// polls flags[t][tid] (relaxed agent, self-throttled by load latency) ->
// syncthreads -> acquire-agent fence -> plain h loads.
// ---------------------------------------------------------------------------
__global__ __launch_bounds__(128) void recurrence(const unsigned short* __restrict__ gx,
                                                  const unsigned short* __restrict__ cand,
                                                  const unsigned short* __restrict__ WghT,
                                                  unsigned short* __restrict__ h0,
                                                  unsigned short* __restrict__ h1,
                                                  unsigned int* __restrict__ flags,
                                                  float* __restrict__ out) {
  const int g = blockIdx.x;          // owns h-cols [8g, 8g+8)
  const int tid = threadIdx.x;
  const int w = tid >> 6;            // batch half
  const int lane = tid & 63;
  const int q = lane >> 4, n = lane & 15;

  __shared__ __align__(16) unsigned short Bs[32 * 1024];   // 64 KB exactly

  // stage Wgh^T slices, XOR-swizzled in 16B units (conflict-free ds_read_b128)
  for (int it = tid; it < 4096; it += 128) {
    int row = it >> 7, c16 = it & 127;
    int tile = row >> 4, rr = row & 15;
    uint4 val = {0u, 0u, 0u, 0u};
    if (tile == 0) {
      int gr = (rr < 8) ? (8 * g + rr) : (1024 + 8 * g + (rr - 8));
      val = ((const uint4*)(WghT + (size_t)gr * HID))[c16];
    } else if (rr < 8) {
      int gr = 2048 + 8 * g + rr;
      val = ((const uint4*)(WghT + (size_t)gr * HID))[c16];
    }
    *(uint4*)((char*)Bs + (size_t)(row * 128 + (c16 ^ (row & 7))) * 16) = val;
  }
  __syncthreads();

  float h_own[4] = {0.f, 0.f, 0.f, 0.f};
  const int c_rp = (n < 8) ? (8 * g + n) : (1024 + 8 * g + (n - 8)); // rho|pi col
  const int c_al = 2048 + 8 * g + (n & 7);                            // alpha col
  const int c_h  = 8 * g + (n & 7);                                   // h/cand col

  const char* b0p = (const char*)Bs + (size_t)n * 2048;
  const char* b1p = b0p + 16 * 2048;

#pragma unroll 1
  for (int t = 0; t < SEQ; ++t) {
    const unsigned short* hc = (t & 1) ? h1 : h0;
    unsigned short* hn = (t & 1) ? h0 : h1;

    // issue gx/cand loads BEFORE the poll: latency hides behind barrier wait
    float g0v[4], g1v[4], vv[4];
#pragma unroll
    for (int r = 0; r < 4; ++r) {
      size_t rb = ((size_t)(w * 16 + q * 4 + r) * SEQ + t);
      g0v[r] = bf2f(gx[rb * G3 + c_rp]);
      g1v[r] = bf2f(gx[rb * G3 + c_al]);
      vv[r]  = bf2f(cand[rb * HID + c_h]);
    }

    // distributed barrier: lane tid waits for producer WG tid's flag.
    // Load latency (~400cy) self-throttles the spin.
    const unsigned int* frow = flags + (size_t)t * NWG;
    while (__hip_atomic_load(&frow[tid], __ATOMIC_RELAXED, __HIP_MEMORY_SCOPE_AGENT) == 0u) {}
    __syncthreads();
    __builtin_amdgcn_fence(__ATOMIC_ACQUIRE, "agent");   // order h loads after flags

    // preact = h(t) @ Wgh_slice
    f32x4_t acc0 = (f32x4_t){0.f, 0.f, 0.f, 0.f};
    f32x4_t acc1 = (f32x4_t){0.f, 0.f, 0.f, 0.f};
    const unsigned short* ha = hc + (size_t)(w * 16 + n) * HID + q * 8;
#pragma unroll 8
    for (int kt = 0; kt < 32; ++kt) {
      bf16x8_t a = *(const bf16x8_t*)(ha + kt * 32);
      int sw = ((kt * 4 + q) ^ (n & 7)) * 16;
      bf16x8_t b0 = *(const bf16x8_t*)(b0p + sw);
      bf16x8_t b1 = *(const bf16x8_t*)(b1p + sw);
      acc0 = __builtin_amdgcn_mfma_f32_16x16x32_bf16(a, b0, acc0, 0, 0, 0);
      acc1 = __builtin_amdgcn_mfma_f32_16x16x32_bf16(a, b1, acc1, 0, 0, 0);
    }

    // gates + carry. D layout: col=lane&15, row(batch)=q*4+r.
#pragma unroll
    for (int r = 0; r < 4; ++r) {
      float s0 = 1.f / (1.f + __expf(-(acc0[r] + g0v[r])));   // rho (n<8) / pi (n>=8)
      float al = 1.f / (1.f + __expf(-(acc1[r] + g1v[r])));   // alpha (n<8)
      float piv = __shfl(s0, q * 16 + 8 + (n & 7), 64);
      if (n < 8) {
        h_own[r] = s0 * (piv * h_own[r] + al * vv[r]);
        hn[(size_t)(w * 16 + q * 4 + r) * HID + c_h] = f2bf(h_own[r]);
      }
    }

    // publish h(t+1): per-wave release (vmcnt drain + L2 wb of ~1KB dirty),
    // then ONE parallel flag store per WG — no cross-WG serialization.
    __builtin_amdgcn_fence(__ATOMIC_RELEASE, "agent");
    __syncthreads();
    if (tid == 0)
      __hip_atomic_store(&flags[(size_t)(t + 1) * NWG + g], 1u,
                         __ATOMIC_RELAXED, __HIP_MEMORY_SCOPE_AGENT);
  }

#pragma unroll
  for (int r = 0; r < 4; ++r)
    if (n < 8)
      out[(size_t)(w * 16 + q * 4 + r) * HID + c_h] = h_own[r];
}

// ---------------------------------------------------------------------------
// launcher
// ---------------------------------------------------------------------------
extern "C" void kernel_launch(void* const* d_in, const int* in_sizes, int n_in,
                              void* d_out, int out_size, void* d_ws, size_t ws_size,
                              hipStream_t stream) {
  const int*   x     = (const int*)d_in[0];
  const float* embed = (const float*)d_in[1];
  const float* Wc    = (const float*)d_in[2];
  const float* bc    = (const float*)d_in[3];
  const float* Wgx   = (const float*)d_in[4];
  const float* bgx   = (const float*)d_in[5];
  const float* Wgh   = (const float*)d_in[6];
  float* out = (float*)d_out;

  char* base = (char*)d_ws;
  unsigned short* e    = (unsigned short*)(base);                       // 32768x1024 bf16 = 64 MiB
  unsigned short* Bp   = (unsigned short*)(base + 67108864);            // 4096x1024 bf16  = 8 MiB
  unsigned short* WghT = (unsigned short*)(base + 75497472);            // 3072x1024 bf16  = 6 MiB
  unsigned short* gxb  = (unsigned short*)(base + 81788928);            // 32768x3072 bf16 = 192 MiB
  unsigned short* cnd  = (unsigned short*)(base + 283115520);           // 32768x1024 bf16 = 64 MiB
  unsigned short* h0   = (unsigned short*)(base + 350224384);           // 32x1024 bf16
  unsigned short* h1   = (unsigned short*)(base + 350289920);           // 32x1024 bf16
  // flags live at base (e region) — e is dead after gemm_fused, and
  // init_state runs after gemm_fused in stream order.
  unsigned int*   flags = (unsigned int*)(base);                        // 1025x128 u32 = 525 KB

  transpose_cast<<<dim3(32, 96), dim3(32, 8), 0, stream>>>(Wgx, Bp, G3);
  transpose_cast<<<dim3(32, 32), dim3(32, 8), 0, stream>>>(Wc, Bp + (size_t)G3 * HID, HID);
  transpose_cast<<<dim3(32, 96), dim3(32, 8), 0, stream>>>(Wgh, WghT, G3);

  gather_cast<<<dim3(NROWS), dim3(256), 0, stream>>>(x, embed, e);

  gemm_fused<<<dim3(256, 32), dim3(256), 0, stream>>>(e, Bp, bgx, bc, gxb, cnd);

  // init barrier flags + h0 AFTER gemm (flags alias e's storage)
  init_state<<<dim3(513), dim3(256), 0, stream>>>(flags, h0);

  // co-residency guaranteed: 128 WGs, 64 KB LDS each -> >=1 per CU on 256 CUs
  void* args[] = {(void*)&gxb, (void*)&cnd, (void*)&WghT, (void*)&h0, (void*)&h1,
                  (void*)&flags, (void*)&out};
  hipLaunchCooperativeKernel((const void*)recurrence, dim3(NWG), dim3(128), args, 0, stream);
}

// Round 4
// 6307.118 us; speedup vs baseline: 5.3972x; 1.9590x over previous
//
#include <hip/hip_runtime.h>
#include <cstdint>
#include <cstddef>

// ---------------------------------------------------------------------------
// Problem constants (ARU recurrence): B=32, S=1024, H=1024, 3H=3072
// ---------------------------------------------------------------------------
#define HID   1024
#define BATCH 32
#define SEQ   1024
#define NROWS 32768   /* BATCH*SEQ */
#define G3    3072
#define NWG   128     /* recurrence workgroups; each owns 8 h-columns */
#define NFLAGS ((SEQ + 1) * NWG)
#define HSLOT 32768   /* elements per h ring slot = BATCH*HID */

typedef __attribute__((ext_vector_type(8))) short bf16x8_t;
typedef __attribute__((ext_vector_type(4))) float f32x4_t;

__device__ __forceinline__ unsigned short f2bf(float f) {
  unsigned u = __float_as_uint(f);
  u += 0x7FFFu + ((u >> 16) & 1u);       // round-to-nearest-even
  return (unsigned short)(u >> 16);
}
__device__ __forceinline__ float bf2f(unsigned short s) {
  return __uint_as_float(((unsigned)s) << 16);
}

// write-through device-coherent 16-bit store (bypasses private L2 dirtiness;
// lands at the fabric/IF$ so other XCDs' first-touch reads see it)
__device__ __forceinline__ void store_short_wt(unsigned short* p, unsigned short v) {
  asm volatile("global_store_short %0, %1, off sc0 sc1"
               :: "v"(p), "v"((unsigned)v) : "memory");
}

// ---------------------------------------------------------------------------
// K0: transpose + cast  W (1024 x N) fp32  ->  WT (N x 1024) bf16
// ---------------------------------------------------------------------------
__global__ __launch_bounds__(256) void transpose_cast(const float* __restrict__ in,
                                                      unsigned short* __restrict__ out,
                                                      int N) {
  __shared__ float tile[32][33];
  int k0 = blockIdx.x * 32, n0 = blockIdx.y * 32;
  int tx = threadIdx.x, ty = threadIdx.y;   // (32,8)
#pragma unroll
  for (int i = 0; i < 4; ++i)
    tile[ty + 8 * i][tx] = in[(size_t)(k0 + ty + 8 * i) * N + n0 + tx];
  __syncthreads();
#pragma unroll
  for (int i = 0; i < 4; ++i)
    out[(size_t)(n0 + ty + 8 * i) * HID + k0 + tx] = f2bf(tile[tx][ty + 8 * i]);
}

// ---------------------------------------------------------------------------
// K1: e = bf16(embed[x])   (32768 x 1024)
// ---------------------------------------------------------------------------
__global__ __launch_bounds__(256) void gather_cast(const int* __restrict__ x,
                                                   const float* __restrict__ embed,
                                                   unsigned short* __restrict__ e) {
  int r = blockIdx.x;
  int t = threadIdx.x;
  int tok = x[r];
  const float4* src = (const float4*)(embed + (size_t)tok * HID);
  float4 v = src[t];
  ushort4 o;
  o.x = f2bf(v.x); o.y = f2bf(v.y); o.z = f2bf(v.z); o.w = f2bf(v.w);
  ((ushort4*)(e + (size_t)r * HID))[t] = o;
}

// ---------------------------------------------------------------------------
// K2: fused GEMM  C = e(32768x1024) @ B'(1024x4096)   [B' stored as (4096x1024) n-major]
//     cols [0,3072): gate_x = C + bgx   (bf16 out)
//     cols [3072,4096): cand = tanh(C + bc) (bf16 out)
// ---------------------------------------------------------------------------
__global__ __launch_bounds__(256) void gemm_fused(const unsigned short* __restrict__ A,
                                                  const unsigned short* __restrict__ B,
                                                  const float* __restrict__ bgx,
                                                  const float* __restrict__ bc,
                                                  unsigned short* __restrict__ gx,
                                                  unsigned short* __restrict__ cand) {
  __shared__ unsigned short As[128 * 32];
  __shared__ unsigned short Bs[128 * 32];
  const int bm = blockIdx.x * 128, bn = blockIdx.y * 128;
  const int t = threadIdx.x;
  const int wave = t >> 6, lane = t & 63;
  const int q = lane >> 4, nidx = lane & 15;
  const int wm = (wave & 1) * 64, wn = (wave >> 1) * 64;
  const int sr = t >> 2;
  const int kofs = (t & 3) * 8;

  f32x4_t acc[4][4];
#pragma unroll
  for (int i = 0; i < 4; ++i)
#pragma unroll
    for (int j = 0; j < 4; ++j) acc[i][j] = (f32x4_t){0.f, 0.f, 0.f, 0.f};

#pragma unroll 1
  for (int kt = 0; kt < HID; kt += 32) {
    __syncthreads();
#pragma unroll
    for (int c = 0; c < 2; ++c) {
      int row = c * 64 + sr;
      *(uint4*)(&As[row * 32 + kofs]) = *(const uint4*)(&A[(size_t)(bm + row) * HID + kt + kofs]);
      *(uint4*)(&Bs[row * 32 + kofs]) = *(const uint4*)(&B[(size_t)(bn + row) * HID + kt + kofs]);
    }
    __syncthreads();
    bf16x8_t af[4], bfr[4];
#pragma unroll
    for (int i = 0; i < 4; ++i)
      af[i] = *(const bf16x8_t*)(&As[(wm + i * 16 + nidx) * 32 + q * 8]);
#pragma unroll
    for (int j = 0; j < 4; ++j)
      bfr[j] = *(const bf16x8_t*)(&Bs[(wn + j * 16 + nidx) * 32 + q * 8]);
#pragma unroll
    for (int i = 0; i < 4; ++i)
#pragma unroll
      for (int j = 0; j < 4; ++j)
        acc[i][j] = __builtin_amdgcn_mfma_f32_16x16x32_bf16(af[i], bfr[j], acc[i][j], 0, 0, 0);
  }

#pragma unroll
  for (int i = 0; i < 4; ++i) {
#pragma unroll
    for (int j = 0; j < 4; ++j) {
#pragma unroll
      for (int reg = 0; reg < 4; ++reg) {
        int m = bm + wm + i * 16 + q * 4 + reg;
        int n = bn + wn + j * 16 + nidx;
        float v = acc[i][j][reg];
        if (n < G3) {
          gx[(size_t)m * G3 + n] = f2bf(v + bgx[n]);
        } else {
          int nc = n - G3;
          cand[(size_t)m * HID + nc] = f2bf(tanhf(v + bc[nc]));
        }
      }
    }
  }
}

// ---------------------------------------------------------------------------
// K3a: init flags + zero h ring slot 0.
// flags[0][g]=1 for all g (h(0)=0 pre-published); flags[1..SEQ][*]=0.
// Plain stores: dispatch-end flush makes them device-visible.
// ---------------------------------------------------------------------------
__global__ __launch_bounds__(256) void init_state(unsigned int* __restrict__ flags,
                                                  unsigned short* __restrict__ ring) {
  int t = blockIdx.x * 256 + threadIdx.x;   // grid 513*256 covers NFLAGS=131200
  if (t < NFLAGS) flags[t] = (t < NWG) ? 1u : 0u;
  if (t < HSLOT) ring[t] = 0;
}

// ---------------------------------------------------------------------------
// K3: recurrence, fence-free steady state.
// h lives in a write-once ring (slot t = h(t)); producers store h with
// write-through sc1 shorts; ONE acquire-agent fence before the loop clears
// stale L2 lines (ring aliases e); per step only: waitcnt + barrier + one
// relaxed sc1 flag store (producer), sc1 flag poll + barrier (consumer),
// plain cached b128 h loads (first touch is always after IF$ has the data).
// ---------------------------------------------------------------------------
__global__ __launch_bounds__(128) void recurrence(const unsigned short* __restrict__ gx,
                                                  const unsigned short* __restrict__ cand,
                                                  const unsigned short* __restrict__ WghT,
                                                  unsigned short* __restrict__ ring,
                                                  unsigned int* __restrict__ flags,
                                                  float* __restrict__ out) {
  const int g = blockIdx.x;          // owns h-cols [8g, 8g+8)
  const int tid = threadIdx.x;
  const int w = tid >> 6;            // batch half
  const int lane = tid & 63;
  const int q = lane >> 4, n = lane & 15;

  __shared__ __align__(16) unsigned short Bs[32 * 1024];   // 64 KB exactly

  // stage Wgh^T slices, XOR-swizzled in 16B units (conflict-free ds_read_b128)
  for (int it = tid; it < 4096; it += 128) {
    int row = it >> 7, c16 = it & 127;
    int tile = row >> 4, rr = row & 15;
    uint4 val = {0u, 0u, 0u, 0u};
    if (tile == 0) {
      int gr = (rr < 8) ? (8 * g + rr) : (1024 + 8 * g + (rr - 8));
      val = ((const uint4*)(WghT + (size_t)gr * HID))[c16];
    } else if (rr < 8) {
      int gr = 2048 + 8 * g + rr;
      val = ((const uint4*)(WghT + (size_t)gr * HID))[c16];
    }
    *(uint4*)((char*)Bs + (size_t)(row * 128 + (c16 ^ (row & 7))) * 16) = val;
  }
  __syncthreads();

  // ONE L2 invalidate for the whole kernel: drop stale lines of the ring
  // region (gemm cached e there) and any replay leftovers. Not in the loop.
  __builtin_amdgcn_fence(__ATOMIC_ACQUIRE, "agent");

  float h_own[4] = {0.f, 0.f, 0.f, 0.f};
  const int c_rp = (n < 8) ? (8 * g + n) : (1024 + 8 * g + (n - 8)); // rho|pi col
  const int c_al = 2048 + 8 * g + (n & 7);                            // alpha col
  const int c_h  = 8 * g + (n & 7);                                   // h/cand col

  const char* b0p = (const char*)Bs + (size_t)n * 2048;
  const char* b1p = b0p + 16 * 2048;

#pragma unroll 1
  for (int t = 0; t < SEQ; ++t) {
    const unsigned short* hc = ring + ((size_t)t << 15);
    unsigned short* hn = ring + ((size_t)(t + 1) << 15);

    // issue gx/cand loads BEFORE the poll: latency hides behind barrier wait
    float g0v[4], g1v[4], vv[4];
#pragma unroll
    for (int r = 0; r < 4; ++r) {
      size_t rb = ((size_t)(w * 16 + q * 4 + r) * SEQ + t);
      g0v[r] = bf2f(gx[rb * G3 + c_rp]);
      g1v[r] = bf2f(gx[rb * G3 + c_al]);
      vv[r]  = bf2f(cand[rb * HID + c_h]);
    }

    // distributed barrier: lane tid waits for producer WG tid's flag (sc1).
    const unsigned int* frow = flags + (size_t)t * NWG;
    while (__hip_atomic_load(&frow[tid], __ATOMIC_RELAXED, __HIP_MEMORY_SCOPE_AGENT) == 0u) {}
    __syncthreads();
    asm volatile("" ::: "memory");   // pin h loads after the barrier

    // preact = h(t) @ Wgh_slice — plain cached loads (first-touch addresses)
    f32x4_t acc0 = (f32x4_t){0.f, 0.f, 0.f, 0.f};
    f32x4_t acc1 = (f32x4_t){0.f, 0.f, 0.f, 0.f};
    const unsigned short* ha = hc + (size_t)(w * 16 + n) * HID + q * 8;
#pragma unroll 8
    for (int kt = 0; kt < 32; ++kt) {
      bf16x8_t a = *(const bf16x8_t*)(ha + kt * 32);
      int sw = ((kt * 4 + q) ^ (n & 7)) * 16;
      bf16x8_t b0 = *(const bf16x8_t*)(b0p + sw);
      bf16x8_t b1 = *(const bf16x8_t*)(b1p + sw);
      acc0 = __builtin_amdgcn_mfma_f32_16x16x32_bf16(a, b0, acc0, 0, 0, 0);
      acc1 = __builtin_amdgcn_mfma_f32_16x16x32_bf16(a, b1, acc1, 0, 0, 0);
    }

    // gates + carry. D layout: col=lane&15, row(batch)=q*4+r.
#pragma unroll
    for (int r = 0; r < 4; ++r) {
      float s0 = 1.f / (1.f + __expf(-(acc0[r] + g0v[r])));   // rho (n<8) / pi (n>=8)
      float al = 1.f / (1.f + __expf(-(acc1[r] + g1v[r])));   // alpha (n<8)
      float piv = __shfl(s0, q * 16 + 8 + (n & 7), 64);
      if (n < 8) {
        h_own[r] = s0 * (piv * h_own[r] + al * vv[r]);
        // write-through sc1: lands at IF$, adjacent lanes coalesce to 16B
        store_short_wt(&hn[(size_t)(w * 16 + q * 4 + r) * HID + c_h], f2bf(h_own[r]));
      }
    }

    // publish: drain own stores to fabric, WG-wide rendezvous, one flag store
    asm volatile("s_waitcnt vmcnt(0)" ::: "memory");
    __syncthreads();
    if (tid == 0)
      __hip_atomic_store(&flags[(size_t)(t + 1) * NWG + g], 1u,
                         __ATOMIC_RELAXED, __HIP_MEMORY_SCOPE_AGENT);
  }

#pragma unroll
  for (int r = 0; r < 4; ++r)
    if (n < 8)
      out[(size_t)(w * 16 + q * 4 + r) * HID + c_h] = h_own[r];
}

// ---------------------------------------------------------------------------
// launcher
// ---------------------------------------------------------------------------
extern "C" void kernel_launch(void* const* d_in, const int* in_sizes, int n_in,
                              void* d_out, int out_size, void* d_ws, size_t ws_size,
                              hipStream_t stream) {
  const int*   x     = (const int*)d_in[0];
  const float* embed = (const float*)d_in[1];
  const float* Wc    = (const float*)d_in[2];
  const float* bc    = (const float*)d_in[3];
  const float* Wgx   = (const float*)d_in[4];
  const float* bgx   = (const float*)d_in[5];
  const float* Wgh   = (const float*)d_in[6];
  float* out = (float*)d_out;

  char* base = (char*)d_ws;
  unsigned short* e    = (unsigned short*)(base);                       // 32768x1024 bf16 = 64 MiB
  unsigned short* Bp   = (unsigned short*)(base + 67108864);            // 4096x1024 bf16  = 8 MiB
  unsigned short* WghT = (unsigned short*)(base + 75497472);            // 3072x1024 bf16  = 6 MiB
  unsigned short* gxb  = (unsigned short*)(base + 81788928);            // 32768x3072 bf16 = 192 MiB
  unsigned short* cnd  = (unsigned short*)(base + 283115520);           // 32768x1024 bf16 = 64 MiB
  // h ring: 1025 slots x 64 KB = 64 MiB + 64 KB. Aliases e (dead after gemm)
  // + first 64 KB of Bp (dead after gemm). Slot t = h(t), write-once.
  unsigned short* ring  = (unsigned short*)(base);
  // flags: (SEQ+1) x NWG u32 = 525 KB, after cnd (old h0/h1 spot)
  unsigned int*   flags = (unsigned int*)(base + 350224384);

  transpose_cast<<<dim3(32, 96), dim3(32, 8), 0, stream>>>(Wgx, Bp, G3);
  transpose_cast<<<dim3(32, 32), dim3(32, 8), 0, stream>>>(Wc, Bp + (size_t)G3 * HID, HID);
  transpose_cast<<<dim3(32, 96), dim3(32, 8), 0, stream>>>(Wgh, WghT, G3);

  gather_cast<<<dim3(NROWS), dim3(256), 0, stream>>>(x, embed, e);

  gemm_fused<<<dim3(256, 32), dim3(256), 0, stream>>>(e, Bp, bgx, bc, gxb, cnd);

  // init flags + ring slot 0 AFTER gemm (ring aliases e's storage)
  init_state<<<dim3(513), dim3(256), 0, stream>>>(flags, ring);

  // co-residency guaranteed: 128 WGs, 64 KB LDS each -> >=1 per CU on 256 CUs
  void* args[] = {(void*)&gxb, (void*)&cnd, (void*)&WghT, (void*)&ring,
                  (void*)&flags, (void*)&out};
  hipLaunchCooperativeKernel((const void*)recurrence, dim3(NWG), dim3(128), args, 0, stream);
}